// Round 1
// baseline (645.134 us; speedup 1.0000x reference)
//
#include <hip/hip_runtime.h>
#include <hip/hip_bf16.h>

#define B_ 128
#define E_ 512
#define H_ 1024
#define S_ 514
#define NEGV -1000000.0f

typedef __attribute__((ext_vector_type(8))) short bf16x8;
typedef __attribute__((ext_vector_type(4))) short s16x4;
typedef __attribute__((ext_vector_type(4))) float f32x4;

__device__ __forceinline__ short f2bf(float f) {
  unsigned u = __builtin_bit_cast(unsigned, f);
  return (short)((u + 0x8000u) >> 16);
}

__device__ __forceinline__ float gelu_f(float x) {
  return 0.5f * x * (1.0f + erff(x * 0.7071067811865475f));
}

// ---------------- prep: Q1[b,h] = query_b @ W1q + b1 ; N1 = null@W1k ; A1 = new@W1k
__global__ void prep_q1(const float* __restrict__ query, const float* __restrict__ W1,
                        const float* __restrict__ b1, const float* __restrict__ nulla,
                        const float* __restrict__ newa, float* __restrict__ Q1,
                        float* __restrict__ N1, float* __restrict__ A1) {
  __shared__ float vec[H_];
  int bid = blockIdx.x;            // 0..519
  int rowIdx = bid >> 2;           // 0..129
  int h = (bid & 3) * 256 + threadIdx.x;
  const float* src;
  int woff;
  if (rowIdx < B_)      { src = query + (size_t)rowIdx * H_; woff = 0; }
  else if (rowIdx == B_){ src = nulla; woff = H_; }
  else                  { src = newa;  woff = H_; }
  for (int i = threadIdx.x; i < H_; i += 256) vec[i] = src[i];
  __syncthreads();
  float acc = (rowIdx < B_) ? b1[h] : 0.f;
  const float* wp = W1 + (size_t)woff * H_ + h;
  #pragma unroll 8
  for (int d = 0; d < H_; ++d) acc += vec[d] * wp[(size_t)d * H_];
  if (rowIdx < B_)       Q1[rowIdx * H_ + h] = acc;
  else if (rowIdx == B_) N1[h] = acc;
  else                   A1[h] = acc;
}

// ---------------- prep: w1kT[n][k] = bf16(W1[H+k][n])  (so GEMM B-frags are contiguous in K)
__global__ void transpose_w1k(const float* __restrict__ W1, short* __restrict__ w1kT) {
  __shared__ float tb[64][65];
  int k0 = (blockIdx.x & 15) * 64;
  int n0 = (blockIdx.x >> 4) * 64;
  int x = threadIdx.x & 63;
  int ty = threadIdx.x >> 6;  // 0..3
  #pragma unroll
  for (int i = 0; i < 16; ++i) {
    int row = i * 4 + ty;  // k_local
    tb[row][x] = W1[(size_t)(H_ + k0 + row) * H_ + n0 + x];
  }
  __syncthreads();
  #pragma unroll
  for (int i = 0; i < 16; ++i) {
    int row = i * 4 + ty;  // n_local
    w1kT[(size_t)(n0 + row) * H_ + k0 + x] = f2bf(tb[x][row]);
  }
}

// ---------------- base scores: b2 +/- mention + mask, plus full null/new slots
__global__ void finalize_base(const int* __restrict__ es, const float* __restrict__ mention,
                              const float* __restrict__ W2, const float* __restrict__ b2,
                              const float* __restrict__ Q1, const float* __restrict__ N1,
                              const float* __restrict__ A1, float* __restrict__ scores) {
  int b = blockIdx.x;
  int t = threadIdx.x;
  float b2v = b2[0], mv = mention[b];
  int esz = es[b];
  for (int s = t; s < S_; s += 256) {
    float base = b2v + (s == 0 ? -mv : mv);
    if (s >= esz + 1 && s <= E_) base += NEGV;
    scores[b * S_ + s] = base;
  }
  float sum0 = 0.f, sum1 = 0.f;
  for (int h = t; h < H_; h += 256) {
    float q = Q1[b * H_ + h], w = W2[h];
    sum0 += gelu_f(q + N1[h]) * w;
    sum1 += gelu_f(q + A1[h]) * w;
  }
  #pragma unroll
  for (int m = 32; m > 0; m >>= 1) { sum0 += __shfl_xor(sum0, m); sum1 += __shfl_xor(sum1, m); }
  __shared__ float red0[4], red1[4];
  int lanei = t & 63, wdi = t >> 6;
  if (lanei == 0) { red0[wdi] = sum0; red1[wdi] = sum1; }
  __syncthreads();
  if (t == 0) {
    scores[b * S_ + 0]      += red0[0] + red0[1] + red0[2] + red0[3];
    scores[b * S_ + S_ - 1] += red1[0] + red1[1] + red1[2] + red1[3];
  }
}

// ---------------- main GEMM (keys @ W1k) fused with +Q1, gelu, *W2, row-reduce, atomicAdd
#define BM 128
#define BN 128
#define BK 64
#define LDT 72  // padded leading dim (bf16 elems): 144B rows -> 2-way-max bank aliasing

__global__ __launch_bounds__(256, 2) void gemm_epilogue(
    const float* __restrict__ keys, const short* __restrict__ w1kT,
    const float* __restrict__ Q1, const float* __restrict__ W2,
    float* __restrict__ scores) {
  __shared__ short As[BM * LDT];
  __shared__ short Bs[BN * LDT];

  int bid = blockIdx.x;
  int cpx = gridDim.x >> 3;                 // 4096 % 8 == 0 -> bijective XCD swizzle
  bid = (bid & 7) * cpx + (bid >> 3);
  int tileM = bid >> 3;
  int tileN = bid & 7;
  int row0 = tileM * BM;
  int col0 = tileN * BN;

  int t = threadIdx.x;
  int lane = t & 63;
  int wid = t >> 6;
  int wr = wid >> 1, wc = wid & 1;
  int l15 = lane & 15, lHi = lane >> 4;

  int asr = t >> 4;          // A stage: row 0..15 (+p*16), 16 float4 per row
  int asc = (t & 15) * 4;
  int bsr = t >> 3;          // B stage: row 0..31 (+p*32), 8 short8 per row
  int bsc = (t & 7) * 8;

  const float* aBase = keys + (size_t)(row0 + asr) * H_ + asc;
  const short* bBase = w1kT + (size_t)(col0 + bsr) * H_ + bsc;

  f32x4 aReg[8];
  bf16x8 bReg[4];
  f32x4 acc[4][4];
  #pragma unroll
  for (int m = 0; m < 4; ++m)
    #pragma unroll
    for (int n = 0; n < 4; ++n) acc[m][n] = (f32x4){0.f, 0.f, 0.f, 0.f};

  #pragma unroll
  for (int p = 0; p < 8; ++p) aReg[p] = *(const f32x4*)(aBase + (size_t)p * 16 * H_);
  #pragma unroll
  for (int p = 0; p < 4; ++p) bReg[p] = *(const bf16x8*)(bBase + (size_t)p * 32 * H_);

  for (int k0 = 0; k0 < H_; k0 += BK) {
    __syncthreads();
    #pragma unroll
    for (int p = 0; p < 8; ++p) {
      s16x4 v;
      #pragma unroll
      for (int j = 0; j < 4; ++j) v[j] = f2bf(aReg[p][j]);
      *(s16x4*)&As[(p * 16 + asr) * LDT + asc] = v;
    }
    #pragma unroll
    for (int p = 0; p < 4; ++p)
      *(bf16x8*)&Bs[(p * 32 + bsr) * LDT + bsc] = bReg[p];
    __syncthreads();
    if (k0 + BK < H_) {  // prefetch next K-slab into regs; overlaps with MFMA below
      #pragma unroll
      for (int p = 0; p < 8; ++p) aReg[p] = *(const f32x4*)(aBase + (size_t)p * 16 * H_ + k0 + BK);
      #pragma unroll
      for (int p = 0; p < 4; ++p) bReg[p] = *(const bf16x8*)(bBase + (size_t)p * 32 * H_ + k0 + BK);
    }
    #pragma unroll
    for (int kk = 0; kk < 2; ++kk) {
      bf16x8 af[4], bfv[4];
      #pragma unroll
      for (int m = 0; m < 4; ++m)
        af[m] = *(const bf16x8*)&As[(wr * 64 + m * 16 + l15) * LDT + kk * 32 + lHi * 8];
      #pragma unroll
      for (int n = 0; n < 4; ++n)
        bfv[n] = *(const bf16x8*)&Bs[(wc * 64 + n * 16 + l15) * LDT + kk * 32 + lHi * 8];
      #pragma unroll
      for (int m = 0; m < 4; ++m)
        #pragma unroll
        for (int n = 0; n < 4; ++n)
          acc[m][n] = __builtin_amdgcn_mfma_f32_16x16x32_bf16(af[m], bfv[n], acc[m][n], 0, 0, 0);
    }
  }

  // epilogue: pre = acc + Q1[b,col]; score_part[row] = sum_col gelu(pre)*W2[col]
  int bIdx = row0 >> 9;  // constant per block (128 | 512)
  float q1v[4], w2v[4];
  #pragma unroll
  for (int n = 0; n < 4; ++n) {
    int col = col0 + wc * 64 + n * 16 + l15;
    q1v[n] = Q1[bIdx * H_ + col];
    w2v[n] = W2[col];
  }
  #pragma unroll
  for (int m = 0; m < 4; ++m) {
    float part[4] = {0.f, 0.f, 0.f, 0.f};
    #pragma unroll
    for (int n = 0; n < 4; ++n)
      #pragma unroll
      for (int i = 0; i < 4; ++i)
        part[i] += gelu_f(acc[m][n][i] + q1v[n]) * w2v[n];
    #pragma unroll
    for (int i = 0; i < 4; ++i) {
      float v = part[i];
      v += __shfl_xor(v, 1);
      v += __shfl_xor(v, 2);
      v += __shfl_xor(v, 4);
      v += __shfl_xor(v, 8);
      if (l15 == 0) {
        int row = row0 + wr * 64 + m * 16 + lHi * 4 + i;
        int s = (row & 511) + 1;
        atomicAdd(&scores[bIdx * S_ + s], v);
      }
    }
  }
}

extern "C" void kernel_launch(void* const* d_in, const int* in_sizes, int n_in,
                              void* d_out, int out_size, void* d_ws, size_t ws_size,
                              hipStream_t stream) {
  const float* query   = (const float*)d_in[0];
  const float* keys    = (const float*)d_in[1];
  const int*   esz     = (const int*)d_in[2];
  const float* mention = (const float*)d_in[3];
  const float* W1      = (const float*)d_in[4];
  const float* b1      = (const float*)d_in[5];
  const float* W2      = (const float*)d_in[6];
  const float* b2      = (const float*)d_in[7];
  const float* nulla   = (const float*)d_in[8];
  const float* newa    = (const float*)d_in[9];
  float* scores = (float*)d_out;

  short* w1kT = (short*)d_ws;                                    // 2 MB
  float* Q1   = (float*)((char*)d_ws + (size_t)2 * 1024 * 1024); // 512 KB
  float* N1   = Q1 + (size_t)B_ * H_;
  float* A1   = N1 + H_;

  prep_q1<<<520, 256, 0, stream>>>(query, W1, b1, nulla, newa, Q1, N1, A1);
  transpose_w1k<<<256, 256, 0, stream>>>(W1, w1kT);
  finalize_base<<<B_, 256, 0, stream>>>(esz, mention, W2, b2, Q1, N1, A1, scores);
  gemm_epilogue<<<4096, 256, 0, stream>>>(keys, w1kT, Q1, W2, scores);
}